// Round 2
// baseline (1561.262 us; speedup 1.0000x reference)
//
#include <hip/hip_runtime.h>

#define FPS_N 32768
#define FPS_M 2048
#define FPS_B 16
#define BLK_PER_B 8
#define FPS_T 576                 // 9 waves: wave 0 = comm, waves 1-8 = scan
#define SCT 512                   // scan threads
#define PTS (FPS_N / BLK_PER_B)   // 4096 points per block
#define PPT (PTS / SCT)           // 8 points per scan thread
#define KPUB 9                    // candidates published per wave (deep pool)
#define RING 128
#define WSTRIDE 640               // 64*9 cand + 64 cut, SINGLE buffer (no parity)

typedef unsigned long long ull;

// u64 max step via DPP (identity-safe: old = self). Verified rounds 11/15-17.
#define DPP_MAX_STEP(ctrl, rmask)                                              \
    {                                                                          \
        unsigned plo = (unsigned)__builtin_amdgcn_update_dpp(                  \
            (int)lo, (int)lo, (ctrl), (rmask), 0xf, false);                    \
        unsigned phi = (unsigned)__builtin_amdgcn_update_dpp(                  \
            (int)hi, (int)hi, (ctrl), (rmask), 0xf, false);                    \
        if (phi > hi || (phi == hi && plo > lo)) { hi = phi; lo = plo; }       \
    }

__device__ __forceinline__ ull wave_max_u64(ull v) {
    unsigned lo = (unsigned)v, hi = (unsigned)(v >> 32);
    DPP_MAX_STEP(0x111, 0xf)
    DPP_MAX_STEP(0x112, 0xf)
    DPP_MAX_STEP(0x114, 0xf)
    DPP_MAX_STEP(0x118, 0xf)
    DPP_MAX_STEP(0x142, 0xa)
    DPP_MAX_STEP(0x143, 0xc)
    unsigned blo = (unsigned)__builtin_amdgcn_readlane((int)lo, 63);
    unsigned bhi = (unsigned)__builtin_amdgcn_readlane((int)hi, 63);
    return ((ull)bhi << 32) | blo;
}

// Wave max of f32 BITS over the domain {non-negative f32, -1.0f sentinel}:
// signed-int order == float order there (sentinel 0xBF800000 is the only
// negative int; all dists have sign bit 0). 4 row_shr DPP steps accumulate
// the row max toward HIGHER lanes (row_shr:N gives lane i the value of lane
// i-N; bound_ctrl=false + old=self keeps under-shifted lanes as self), so
// after 1/2/4/8 the row max sits in lane 15 of each 16-lane row. v7 BUG
// (fixed here): reading lanes 0/16/32/48 sampled single lanes, not row
// maxima -> wrong wave max -> livelock + wrong output. Read 15/31/47/63.
__device__ __forceinline__ unsigned wave_max_bits(unsigned v) {
    int m = (int)v;
#define DPP_IMAX_STEP(ctrl)                                                    \
    {                                                                          \
        int p = __builtin_amdgcn_update_dpp((int)m, (int)m, (ctrl), 0xf, 0xf,  \
                                            false);                            \
        m = p > m ? p : m;                                                     \
    }
    DPP_IMAX_STEP(0x111)   // row_shr:1
    DPP_IMAX_STEP(0x112)   // row_shr:2
    DPP_IMAX_STEP(0x114)   // row_shr:4
    DPP_IMAX_STEP(0x118)   // row_shr:8 -> lane 15 of each row = row max
    int r0 = __builtin_amdgcn_readlane(m, 15);
    int r1 = __builtin_amdgcn_readlane(m, 31);
    int r2 = __builtin_amdgcn_readlane(m, 47);
    int r3 = __builtin_amdgcn_readlane(m, 63);
    int a = r0 > r1 ? r0 : r1;
    int b = r2 > r3 ? r2 : r3;
    return (unsigned)(a > b ? a : b);
}

// u32 wave min (identity-safe), broadcast from lane 63. Rare-tie path only.
__device__ __forceinline__ unsigned wave_min_u32(unsigned v) {
    unsigned m = v;
#define DPP_UMIN_STEP(ctrl, rmask)                                             \
    {                                                                          \
        unsigned p = (unsigned)__builtin_amdgcn_update_dpp(                    \
            (int)m, (int)m, (ctrl), (rmask), 0xf, false);                      \
        if (p < m) m = p;                                                      \
    }
    DPP_UMIN_STEP(0x111, 0xf)
    DPP_UMIN_STEP(0x112, 0xf)
    DPP_UMIN_STEP(0x114, 0xf)
    DPP_UMIN_STEP(0x118, 0xf)
    DPP_UMIN_STEP(0x142, 0xa)
    DPP_UMIN_STEP(0x143, 0xc)
    return (unsigned)__builtin_amdgcn_readlane((int)m, 63);
}

__device__ __forceinline__ float readlane_f(float v, int l) {
    return __uint_as_float(
        (unsigned)__builtin_amdgcn_readlane((int)__float_as_uint(v), l));
}

// EXACT LAZY-BATCHED FPS v8 = v7 (deep pool) + wave_max_bits lane fix.
// v6 post-mortem: halving B-phase issue cost changed nothing (1497->1493us)
// => chain dominated by the fixed per-epoch MALL round-trip, not B. So:
// amortize the round-trip over more selections per epoch.
//   KPUB 4->9: scan waves publish ranks 1..9 + rank-10-as-cut (10 rounds).
//   Exactness unchanged: u64 word order (dist desc, then lower global index)
//   == reference argmax preference; every unpublished point's word < its
//   wave's rank-10 word <= vcutg, so "pop while W > vcutg" stays bit-exact.
//   >=1 pop/epoch guaranteed: global-max word > its own wave's rank-10 word
//   and > every other wave's rank-10 word => W > vcutg at least once.
//   Parity dropped (single 640-word buffer, same 80KB): scans publish e+1
//   only after etot(e), which comm posts only after catching ALL epoch-e
//   words -> no overwrite-before-consume. Tags (12-bit epoch) unchanged;
//   e <= 2047 < 0xAAA poison < 4096.
//   Cheap reduces: wave max via 4-step row_shr int-DPP + 4 readlane (rows'
//   lane 15/31/47/63) + scalar combine; comm per-pop max uses a hi-bits
//   fast path, falling back to the verified u64 DPP reduce on exact dist
//   ties. Catch loop issues all pending polls before any tag check so the
//   10 words pipeline in one MALL latency.
// Protocol otherwise = v6: relaxed agent publishes, self-validating tags,
// comm sims while pool max > vcutg, LDS ring + monotone release tags, zero
// steady-state barriers, s_sleep(1) on every spin miss. Ring reuse at +128
// post-consumption (posted<RING per epoch + full apply before next epoch).
// Numerics bit-exact: contract off, (dx*dx+dy*dy)+dz*dz, min via ?:, no fma.
__global__ __launch_bounds__(FPS_T)
__attribute__((amdgpu_waves_per_eu(1)))
void fps_kernel(const float* __restrict__ pts, float* __restrict__ out,
                ull* __restrict__ ws) {
#pragma clang fp contract(off)
    __shared__ float srx[RING], sry[RING], srz[RING];
    __shared__ unsigned rtag[RING];
    __shared__ unsigned etot;           // (epoch<<16) | last_posted_row

    const int blk = blockIdx.x;
    const int b = blk & 15;             // batch
    const int j = blk >> 4;             // block-within-batch 0..7
    const int tid = threadIdx.x;
    const int lane = tid & 63;
    const float* __restrict__ X = pts + (size_t)b * 3 * FPS_N;
    const float* __restrict__ Y = X + FPS_N;
    const float* __restrict__ Z = Y + FPS_N;
    const int off = j * PTS;
    float* __restrict__ outb = out + (size_t)b * 3 * FPS_M;
    ull* __restrict__ wsb = ws + (size_t)b * WSTRIDE;

    for (int q = tid; q < RING; q += FPS_T) rtag[q] = 0;
    if (tid == 0) etot = 0;
    __syncthreads();                    // only barrier (pre-loop)

    const float p0x = X[0], p0y = Y[0], p0z = Z[0];

    if (tid < 64) {
        // ================= comm wave =================
        if (j == 0 && lane == 0) {      // row 0 = point 0
            outb[0] = p0x; outb[FPS_M] = p0y; outb[2 * FPS_M] = p0z;
        }
        ull* const ca = wsb + lane * KPUB;   // lane l polls wave l
        ull* const cu = wsb + 576 + lane;
        int last = 0;
        for (unsigned e = 1; last < FPS_M - 1; ++e) {
            ull cv[KPUB];
            float ccx[KPUB], ccy[KPUB], ccz[KPUB];
#pragma unroll
            for (int c = 0; c < KPUB; ++c) {
                cv[c] = 0; ccx[c] = 0.0f; ccy[c] = 0.0f; ccz[c] = 0.0f;
            }
            unsigned kcm = 0;
            bool kw = false;
            ull cw = 0;
            for (int it = 0; it < (1 << 25); ++it) {
                ull pv[KPUB + 1];
                // issue ALL pending polls first so they pipeline in one
                // MALL round-trip, then check tags / prefetch coords.
#pragma unroll
                for (int c = 0; c < KPUB; ++c)
                    pv[c] = (kcm & (1u << c))
                                ? 0
                                : __hip_atomic_load(ca + c, __ATOMIC_RELAXED,
                                                    __HIP_MEMORY_SCOPE_AGENT);
                if (!kw)
                    pv[KPUB] = __hip_atomic_load(cu, __ATOMIC_RELAXED,
                                                 __HIP_MEMORY_SCOPE_AGENT);
#pragma unroll
                for (int c = 0; c < KPUB; ++c) {
                    if (!(kcm & (1u << c)) &&
                        (unsigned)(pv[c] & 0xFFFull) == e) {
                        cv[c] = pv[c];
                        kcm |= 1u << c;
                        const int g = 32767 - (int)((pv[c] >> 17) & 0x7FFFull);
                        ccx[c] = X[g];  // prefetch during residual poll
                        ccy[c] = Y[g];
                        ccz[c] = Z[g];
                    }
                }
                if (!kw) {
                    cw = pv[KPUB];
                    kw = ((unsigned)(cw & 0xFFFull) == e);
                }
                if (__all((kcm == ((1u << KPUB) - 1)) && kw)) break;
                __builtin_amdgcn_s_sleep(1);    // miss: free the SIMD
            }
            const ull vcutg = wave_max_u64(cw); // max of 64 wave rank-10s
            int posted = 0;
            while (last < FPS_M - 1 && posted < RING) {
                ull m = cv[0];
#pragma unroll
                for (int c = 1; c < KPUB; ++c)
                    if (cv[c] > m) m = cv[c];
                // hi-bits fast path for the wave max word; exact-tie fallback
                const unsigned mhi = (unsigned)(m >> 32);
                const unsigned Whi = wave_max_bits(mhi);
                const ull tb = __ballot(mhi == Whi);
                ull W;
                if (__popcll(tb) == 1) {
                    const int wl0 = (int)(__ffsll((long long)tb) - 1);
                    const unsigned wlo = (unsigned)__builtin_amdgcn_readlane(
                        (int)(unsigned)(m & 0xFFFFFFFFull), wl0);
                    W = ((ull)Whi << 32) | wlo;
                } else {
                    W = wave_max_u64(m);        // exact dist tie (rare)
                }
                if (W <= vcutg) break;
                bool own = false;
                float sx = 0.0f, sy = 0.0f, sz = 0.0f;
#pragma unroll
                for (int c = 0; c < KPUB; ++c) {
                    const bool h = (cv[c] == W);  // words globally unique
                    own |= h;
                    sx = h ? ccx[c] : sx;
                    sy = h ? ccy[c] : sy;
                    sz = h ? ccz[c] : sz;
                    cv[c] = h ? 0 : cv[c];        // consume
                }
                const ull mk = __ballot(own);     // exactly one bit
                const int wl = __ffsll((long long)mk) - 1;
                const float wx = readlane_f(sx, wl);
                const float wy = readlane_f(sy, wl);
                const float wz = readlane_f(sz, wl);
                // update pool (same IEEE ops as the batched apply)
#pragma unroll
                for (int c = 0; c < KPUB; ++c) {
                    float dx = ccx[c] - wx, dy = ccy[c] - wy, dz = ccz[c] - wz;
                    float d = (dx * dx + dy * dy) + dz * dz;
                    float df = __uint_as_float((unsigned)(cv[c] >> 32));
                    float nd = d < df ? d : df;   // consumed (0) stays 0
                    cv[c] = ((ull)__float_as_uint(nd) << 32)
                          | (cv[c] & 0xFFFFFFFFull);
                }
                ++last; ++posted;
                const int slot = last & (RING - 1);
                if (lane == 0) {                  // post to ring, release tag
                    srx[slot] = wx; sry[slot] = wy; srz[slot] = wz;
                    __hip_atomic_store(&rtag[slot], (unsigned)last,
                                       __ATOMIC_RELEASE,
                                       __HIP_MEMORY_SCOPE_WORKGROUP);
                }
            }
            if (lane == 0)
                __hip_atomic_store(&etot, (e << 16) | (unsigned)last,
                                   __ATOMIC_RELAXED, __HIP_MEMORY_SCOPE_WORKGROUP);
        }
    } else {
        // ================= scan waves =================
        const int st = tid - 64;        // 0..511
        const int w = (tid >> 6) - 1;   // scan wave 0..7
        const int wid = j * 8 + w;      // wave id within batch 0..63
        ull* const myc = wsb + (size_t)wid * KPUB;
        ull* const mycut = wsb + 576 + wid;
        float cx[PPT], cy[PPT], cz[PPT], dist[PPT];
#pragma unroll
        for (int k = 0; k < PPT; ++k) { // coords in regs; apply p0 inline
            const int g = off + k * SCT + st;
            cx[k] = X[g]; cy[k] = Y[g]; cz[k] = Z[g];
            float dx = cx[k] - p0x, dy = cy[k] - p0y, dz = cz[k] - p0z;
            dist[k] = (dx * dx + dy * dy) + dz * dz;
        }
        const int goff = off + st;      // g(k) = goff + k*SCT, increasing in k
        unsigned applied = 0;
        for (unsigned e = 1;; ++e) {
            // ---- B: top-10 extraction (bit-compares; exact tie resolve) ----
            float fd[PPT];
#pragma unroll
            for (int k = 0; k < PPT; ++k) fd[k] = dist[k];
            for (int r = 0; r < KPUB + 1; ++r) {
                float m = fd[0];
#pragma unroll
                for (int k = 1; k < PPT; ++k) m = fmaxf(m, fd[k]);
                const unsigned Wb = wave_max_bits(__float_as_uint(m));
                // lane-local lowest-index holder of W (descending overwrite)
                unsigned mg = 0xFFFFFFFFu;
#pragma unroll
                for (int k = PPT - 1; k >= 0; --k)
                    if (__float_as_uint(fd[k]) == Wb)
                        mg = (unsigned)(goff + k * SCT);
                const ull mk = __ballot(mg != 0xFFFFFFFFu);   // >= 1 bit
                unsigned gw;
                if (__popcll(mk) == 1) {          // unique holder (common)
                    gw = (unsigned)__builtin_amdgcn_readlane(
                        (int)mg, (int)(__ffsll((long long)mk) - 1));
                } else {                          // exact dist tie (rare)
                    gw = wave_min_u32(mg);
                }
                const ull word = ((ull)Wb << 32)
                               | ((ull)(32767u - gw) << 17) | (ull)e;
                if (r < KPUB) {
#pragma unroll
                    for (int k = 0; k < PPT; ++k)  // mask exactly the winner
                        if ((unsigned)(goff + k * SCT) == gw)
                            fd[k] = -1.0f;         // < every real dist (>=+0)
                    if (lane == r)                 // incremental publish
                        __hip_atomic_store(myc + r, word,
                                           __ATOMIC_RELAXED,
                                           __HIP_MEMORY_SCOPE_AGENT);
                } else {
                    if (lane == KPUB)              // the cut (rank-10)
                        __hip_atomic_store(mycut, word,
                                           __ATOMIC_RELAXED,
                                           __HIP_MEMORY_SCOPE_AGENT);
                }
            }
            // ---- apply: consume ring entries as posted; sleep when idle ----
            unsigned last_row = 0;
            bool have = false;
            for (;;) {
                bool did = false;
                if (!have) {
                    unsigned u = __hip_atomic_load(&etot, __ATOMIC_RELAXED,
                                                   __HIP_MEMORY_SCOPE_WORKGROUP);
                    if ((u >> 16) == e) { last_row = u & 0xFFFFu; have = true; did = true; }
                }
                const unsigned want = applied + 1;
                if (!have || want <= last_row) {
                    const int slot = (int)(want & (RING - 1));
                    if (__hip_atomic_load(&rtag[slot], __ATOMIC_ACQUIRE,
                                          __HIP_MEMORY_SCOPE_WORKGROUP) == want) {
                        const float wx = srx[slot], wy = sry[slot], wz = srz[slot];
#pragma unroll
                        for (int k = 0; k < PPT; ++k) {
                            float dx = cx[k] - wx, dy = cy[k] - wy, dz = cz[k] - wz;
                            float d = (dx * dx + dy * dy) + dz * dz;
                            dist[k] = d < dist[k] ? d : dist[k];
                        }
                        if (j == 0 && w == 0 && lane < 3) {   // emit row
                            float cvv = lane == 0 ? wx : (lane == 1 ? wy : wz);
                            outb[(size_t)lane * FPS_M + want] = cvv;
                        }
                        applied = want;
                        did = true;
                    }
                }
                if (have && applied == last_row) break;
                if (!did) __builtin_amdgcn_s_sleep(1);  // idle: free the SIMD
            }
            if (last_row >= FPS_M - 1) break;
        }
    }
}

extern "C" void kernel_launch(void* const* d_in, const int* in_sizes, int n_in,
                              void* d_out, int out_size, void* d_ws, size_t ws_size,
                              hipStream_t stream) {
    const float* pts = (const float*)d_in[0];   // [16, 3, 32768] fp32
    float* out = (float*)d_out;                 // [16, 3, 2048] fp32
    ull* ws = (ull*)d_ws;                       // 16 x 640 words = 80 KB used
    void* args[] = { (void*)&pts, (void*)&out, (void*)&ws };
    hipLaunchCooperativeKernel((const void*)fps_kernel,
                               dim3(FPS_B * BLK_PER_B), dim3(FPS_T),
                               args, 0, stream);
}

// Round 3
// 1157.269 us; speedup vs baseline: 1.3491x; 1.3491x over previous
//
#include <hip/hip_runtime.h>

#define FPS_N 32768
#define FPS_M 2048
#define FPS_B 16
#define BLK_PER_B 8
#define FPS_T 576                 // 9 waves: wave 0 = comm, waves 1-8 = scan
#define SCT 512                   // scan threads
#define PTS (FPS_N / BLK_PER_B)   // 4096 points per block
#define PPT (PTS / SCT)           // 8 points per scan thread
#define KPUB 4                    // candidates published per wave
#define RING 128
#define WSTRIDE 320               // rank-major: r*64+wid (r=0..3), cut 256+wid

typedef unsigned long long ull;

// u64 max step via DPP (identity-safe: old = self). Verified rounds 11/15-17.
#define DPP_MAX_STEP(ctrl, rmask)                                              \
    {                                                                          \
        unsigned plo = (unsigned)__builtin_amdgcn_update_dpp(                  \
            (int)lo, (int)lo, (ctrl), (rmask), 0xf, false);                    \
        unsigned phi = (unsigned)__builtin_amdgcn_update_dpp(                  \
            (int)hi, (int)hi, (ctrl), (rmask), 0xf, false);                    \
        if (phi > hi || (phi == hi && plo > lo)) { hi = phi; lo = plo; }       \
    }

__device__ __forceinline__ ull wave_max_u64(ull v) {
    unsigned lo = (unsigned)v, hi = (unsigned)(v >> 32);
    DPP_MAX_STEP(0x111, 0xf)
    DPP_MAX_STEP(0x112, 0xf)
    DPP_MAX_STEP(0x114, 0xf)
    DPP_MAX_STEP(0x118, 0xf)
    DPP_MAX_STEP(0x142, 0xa)
    DPP_MAX_STEP(0x143, 0xc)
    unsigned blo = (unsigned)__builtin_amdgcn_readlane((int)lo, 63);
    unsigned bhi = (unsigned)__builtin_amdgcn_readlane((int)hi, 63);
    return ((ull)bhi << 32) | blo;
}

// Wave max of f32 BITS over the domain {non-negative f32, -1.0f sentinel}:
// signed-int order == float order there. 4 row_shr DPP steps accumulate the
// row max toward HIGHER lanes (row_shr:N gives lane i the value of lane i-N;
// bound_ctrl=false + old=self keeps under-shifted lanes as self), so after
// 1/2/4/8 the row max sits in lane 15/31/47/63. Verified on HW in v8 run.
__device__ __forceinline__ unsigned wave_max_bits(unsigned v) {
    int m = (int)v;
#define DPP_IMAX_STEP(ctrl)                                                    \
    {                                                                          \
        int p = __builtin_amdgcn_update_dpp((int)m, (int)m, (ctrl), 0xf, 0xf,  \
                                            false);                            \
        m = p > m ? p : m;                                                     \
    }
    DPP_IMAX_STEP(0x111)   // row_shr:1
    DPP_IMAX_STEP(0x112)   // row_shr:2
    DPP_IMAX_STEP(0x114)   // row_shr:4
    DPP_IMAX_STEP(0x118)   // row_shr:8 -> lane 15 of each row = row max
    int r0 = __builtin_amdgcn_readlane(m, 15);
    int r1 = __builtin_amdgcn_readlane(m, 31);
    int r2 = __builtin_amdgcn_readlane(m, 47);
    int r3 = __builtin_amdgcn_readlane(m, 63);
    int a = r0 > r1 ? r0 : r1;
    int b = r2 > r3 ? r2 : r3;
    return (unsigned)(a > b ? a : b);
}

// u32 wave min (identity-safe), broadcast from lane 63. Rare-tie path only.
__device__ __forceinline__ unsigned wave_min_u32(unsigned v) {
    unsigned m = v;
#define DPP_UMIN_STEP(ctrl, rmask)                                             \
    {                                                                          \
        unsigned p = (unsigned)__builtin_amdgcn_update_dpp(                    \
            (int)m, (int)m, (ctrl), (rmask), 0xf, false);                      \
        if (p < m) m = p;                                                      \
    }
    DPP_UMIN_STEP(0x111, 0xf)
    DPP_UMIN_STEP(0x112, 0xf)
    DPP_UMIN_STEP(0x114, 0xf)
    DPP_UMIN_STEP(0x118, 0xf)
    DPP_UMIN_STEP(0x142, 0xa)
    DPP_UMIN_STEP(0x143, 0xc)
    return (unsigned)__builtin_amdgcn_readlane((int)m, 63);
}

__device__ __forceinline__ float readlane_f(float v, int l) {
    return __uint_as_float(
        (unsigned)__builtin_amdgcn_readlane((int)__float_as_uint(v), l));
}

// EXACT LAZY-BATCHED FPS v9 — coalesced mailbox. Post-mortems:
//   v6 (B-phase halved): no change -> B not the wall.
//   v8 (KPUB 4->9): 1493->1555us, FETCH 9.3->16.9MB -> k-sweep axis dead
//     (pool decay binds pops/epoch, not the cut) AND scattered polls grew:
//     each poll instr read 64 lanes x 8B at 72B stride = 64 cache lines.
// Remaining per-epoch chain (~4.0k cyc): B ~0.85k, pops ~0.3k, apply ~0.2k,
// publish->catch round-trip ~2.6k <- the wall. This version attacks it:
//   TRANSPOSED LAYOUT (one delta vs v6): rank-major mailbox, word for rank r
//   of wave wid at ws[r*64+wid], cut at ws[256+wid]. Comm lane l polls
//   {l, 64+l, 128+l, 192+l, 256+l}: every poll instruction is a contiguous
//   512B read (8 lines) instead of a 32-line gather -> 4x fewer MALL lines,
//   shorter vmcnt drain per poll, less congestion from 8 redundant pollers.
// Retained from the v8 run (HW-verified, absmax 0.0): single 320-word
// buffer (scan publishes e+1 only after etot(e), which comm posts only
// after catching ALL epoch-e words -> no overwrite-before-consume), fixed
// wave_max_bits short reduce, hi-bits fast-path pop with u64-DPP tie
// fallback, pipelined issue-all-loads-then-check poll.
// Exactness: u64 word order (dist desc, then lower global index) == ref
// argmax preference; unpublished points' words < own wave's rank-5 word <=
// vcutg; pop while W > vcutg. >=1 pop/epoch (global max beats every cut).
// Tags: 12-bit epoch, e <= 2047; ws 0xAA poison field 0xAAA never matches;
// zeros never match. Ring reuse at +128 provably post-consumption.
// Numerics bit-exact: contract off, (dx*dx+dy*dy)+dz*dz, min via ?:, no fma.
__global__ __launch_bounds__(FPS_T)
__attribute__((amdgpu_waves_per_eu(1)))
void fps_kernel(const float* __restrict__ pts, float* __restrict__ out,
                ull* __restrict__ ws) {
#pragma clang fp contract(off)
    __shared__ float srx[RING], sry[RING], srz[RING];
    __shared__ unsigned rtag[RING];
    __shared__ unsigned etot;           // (epoch<<16) | last_posted_row

    const int blk = blockIdx.x;
    const int b = blk & 15;             // batch
    const int j = blk >> 4;             // block-within-batch 0..7
    const int tid = threadIdx.x;
    const int lane = tid & 63;
    const float* __restrict__ X = pts + (size_t)b * 3 * FPS_N;
    const float* __restrict__ Y = X + FPS_N;
    const float* __restrict__ Z = Y + FPS_N;
    const int off = j * PTS;
    float* __restrict__ outb = out + (size_t)b * 3 * FPS_M;
    ull* __restrict__ wsb = ws + (size_t)b * WSTRIDE;

    for (int q = tid; q < RING; q += FPS_T) rtag[q] = 0;
    if (tid == 0) etot = 0;
    __syncthreads();                    // only barrier (pre-loop)

    const float p0x = X[0], p0y = Y[0], p0z = Z[0];

    if (tid < 64) {
        // ================= comm wave =================
        if (j == 0 && lane == 0) {      // row 0 = point 0
            outb[0] = p0x; outb[FPS_M] = p0y; outb[2 * FPS_M] = p0z;
        }
        int last = 0;
        for (unsigned e = 1; last < FPS_M - 1; ++e) {
            ull cv[KPUB];
            float ccx[KPUB], ccy[KPUB], ccz[KPUB];
#pragma unroll
            for (int c = 0; c < KPUB; ++c) {
                cv[c] = 0; ccx[c] = 0.0f; ccy[c] = 0.0f; ccz[c] = 0.0f;
            }
            unsigned kcm = 0;
            bool kw = false;
            ull cw = 0;
            for (int it = 0; it < (1 << 25); ++it) {
                ull pv[KPUB + 1];
                // issue ALL pending polls first (each is a coalesced 512B
                // read: lane stride 8B), then check tags / prefetch coords.
#pragma unroll
                for (int c = 0; c < KPUB; ++c)
                    pv[c] = (kcm & (1u << c))
                                ? 0
                                : __hip_atomic_load(wsb + c * 64 + lane,
                                                    __ATOMIC_RELAXED,
                                                    __HIP_MEMORY_SCOPE_AGENT);
                if (!kw)
                    pv[KPUB] = __hip_atomic_load(wsb + 256 + lane,
                                                 __ATOMIC_RELAXED,
                                                 __HIP_MEMORY_SCOPE_AGENT);
#pragma unroll
                for (int c = 0; c < KPUB; ++c) {
                    if (!(kcm & (1u << c)) &&
                        (unsigned)(pv[c] & 0xFFFull) == e) {
                        cv[c] = pv[c];
                        kcm |= 1u << c;
                        const int g = 32767 - (int)((pv[c] >> 17) & 0x7FFFull);
                        ccx[c] = X[g];  // prefetch during residual poll
                        ccy[c] = Y[g];
                        ccz[c] = Z[g];
                    }
                }
                if (!kw) {
                    cw = pv[KPUB];
                    kw = ((unsigned)(cw & 0xFFFull) == e);
                }
                if (__all((kcm == ((1u << KPUB) - 1)) && kw)) break;
                __builtin_amdgcn_s_sleep(1);    // miss: free the SIMD
            }
            const ull vcutg = wave_max_u64(cw); // max of 64 wave rank-5s
            int posted = 0;
            while (last < FPS_M - 1 && posted < RING) {
                ull m = cv[0];
#pragma unroll
                for (int c = 1; c < KPUB; ++c)
                    if (cv[c] > m) m = cv[c];
                // hi-bits fast path for the wave max word; exact-tie fallback
                const unsigned mhi = (unsigned)(m >> 32);
                const unsigned Whi = wave_max_bits(mhi);
                const ull tb = __ballot(mhi == Whi);
                ull W;
                if (__popcll(tb) == 1) {
                    const int wl0 = (int)(__ffsll((long long)tb) - 1);
                    const unsigned wlo = (unsigned)__builtin_amdgcn_readlane(
                        (int)(unsigned)(m & 0xFFFFFFFFull), wl0);
                    W = ((ull)Whi << 32) | wlo;
                } else {
                    W = wave_max_u64(m);        // exact dist tie (rare)
                }
                if (W <= vcutg) break;
                bool own = false;
                float sx = 0.0f, sy = 0.0f, sz = 0.0f;
#pragma unroll
                for (int c = 0; c < KPUB; ++c) {
                    const bool h = (cv[c] == W);  // words globally unique
                    own |= h;
                    sx = h ? ccx[c] : sx;
                    sy = h ? ccy[c] : sy;
                    sz = h ? ccz[c] : sz;
                    cv[c] = h ? 0 : cv[c];        // consume
                }
                const ull mk = __ballot(own);     // exactly one bit
                const int wl = __ffsll((long long)mk) - 1;
                const float wx = readlane_f(sx, wl);
                const float wy = readlane_f(sy, wl);
                const float wz = readlane_f(sz, wl);
                // update pool (same IEEE ops as the batched apply)
#pragma unroll
                for (int c = 0; c < KPUB; ++c) {
                    float dx = ccx[c] - wx, dy = ccy[c] - wy, dz = ccz[c] - wz;
                    float d = (dx * dx + dy * dy) + dz * dz;
                    float df = __uint_as_float((unsigned)(cv[c] >> 32));
                    float nd = d < df ? d : df;   // consumed (0) stays 0
                    cv[c] = ((ull)__float_as_uint(nd) << 32)
                          | (cv[c] & 0xFFFFFFFFull);
                }
                ++last; ++posted;
                const int slot = last & (RING - 1);
                if (lane == 0) {                  // post to ring, release tag
                    srx[slot] = wx; sry[slot] = wy; srz[slot] = wz;
                    __hip_atomic_store(&rtag[slot], (unsigned)last,
                                       __ATOMIC_RELEASE,
                                       __HIP_MEMORY_SCOPE_WORKGROUP);
                }
            }
            if (lane == 0)
                __hip_atomic_store(&etot, (e << 16) | (unsigned)last,
                                   __ATOMIC_RELAXED, __HIP_MEMORY_SCOPE_WORKGROUP);
        }
    } else {
        // ================= scan waves =================
        const int st = tid - 64;        // 0..511
        const int w = (tid >> 6) - 1;   // scan wave 0..7
        const int wid = j * 8 + w;      // wave id within batch 0..63
        float cx[PPT], cy[PPT], cz[PPT], dist[PPT];
#pragma unroll
        for (int k = 0; k < PPT; ++k) { // coords in regs; apply p0 inline
            const int g = off + k * SCT + st;
            cx[k] = X[g]; cy[k] = Y[g]; cz[k] = Z[g];
            float dx = cx[k] - p0x, dy = cy[k] - p0y, dz = cz[k] - p0z;
            dist[k] = (dx * dx + dy * dy) + dz * dz;
        }
        const int goff = off + st;      // g(k) = goff + k*SCT, increasing in k
        unsigned applied = 0;
        for (unsigned e = 1;; ++e) {
            // ---- B: top-5 extraction (bit-compares; exact tie resolve) ----
            float fd[PPT];
#pragma unroll
            for (int k = 0; k < PPT; ++k) fd[k] = dist[k];
            for (int r = 0; r < KPUB + 1; ++r) {
                float m = fd[0];
#pragma unroll
                for (int k = 1; k < PPT; ++k) m = fmaxf(m, fd[k]);
                const unsigned Wb = wave_max_bits(__float_as_uint(m));
                // lane-local lowest-index holder of W (descending overwrite)
                unsigned mg = 0xFFFFFFFFu;
#pragma unroll
                for (int k = PPT - 1; k >= 0; --k)
                    if (__float_as_uint(fd[k]) == Wb)
                        mg = (unsigned)(goff + k * SCT);
                const ull mk = __ballot(mg != 0xFFFFFFFFu);   // >= 1 bit
                unsigned gw;
                if (__popcll(mk) == 1) {          // unique holder (common)
                    gw = (unsigned)__builtin_amdgcn_readlane(
                        (int)mg, (int)(__ffsll((long long)mk) - 1));
                } else {                          // exact dist tie (rare)
                    gw = wave_min_u32(mg);
                }
                const ull word = ((ull)Wb << 32)
                               | ((ull)(32767u - gw) << 17) | (ull)e;
                if (r < KPUB) {
#pragma unroll
                    for (int k = 0; k < PPT; ++k)  // mask exactly the winner
                        if ((unsigned)(goff + k * SCT) == gw)
                            fd[k] = -1.0f;         // < every real dist (>=+0)
                    if (lane == r)                 // rank-major publish
                        __hip_atomic_store(wsb + r * 64 + wid, word,
                                           __ATOMIC_RELAXED,
                                           __HIP_MEMORY_SCOPE_AGENT);
                } else {
                    if (lane == KPUB)              // the cut (rank-5)
                        __hip_atomic_store(wsb + 256 + wid, word,
                                           __ATOMIC_RELAXED,
                                           __HIP_MEMORY_SCOPE_AGENT);
                }
            }
            // ---- apply: consume ring entries as posted; sleep when idle ----
            unsigned last_row = 0;
            bool have = false;
            for (;;) {
                bool did = false;
                if (!have) {
                    unsigned u = __hip_atomic_load(&etot, __ATOMIC_RELAXED,
                                                   __HIP_MEMORY_SCOPE_WORKGROUP);
                    if ((u >> 16) == e) { last_row = u & 0xFFFFu; have = true; did = true; }
                }
                const unsigned want = applied + 1;
                if (!have || want <= last_row) {
                    const int slot = (int)(want & (RING - 1));
                    if (__hip_atomic_load(&rtag[slot], __ATOMIC_ACQUIRE,
                                          __HIP_MEMORY_SCOPE_WORKGROUP) == want) {
                        const float wx = srx[slot], wy = sry[slot], wz = srz[slot];
#pragma unroll
                        for (int k = 0; k < PPT; ++k) {
                            float dx = cx[k] - wx, dy = cy[k] - wy, dz = cz[k] - wz;
                            float d = (dx * dx + dy * dy) + dz * dz;
                            dist[k] = d < dist[k] ? d : dist[k];
                        }
                        if (j == 0 && w == 0 && lane < 3) {   // emit row
                            float cvv = lane == 0 ? wx : (lane == 1 ? wy : wz);
                            outb[(size_t)lane * FPS_M + want] = cvv;
                        }
                        applied = want;
                        did = true;
                    }
                }
                if (have && applied == last_row) break;
                if (!did) __builtin_amdgcn_s_sleep(1);  // idle: free the SIMD
            }
            if (last_row >= FPS_M - 1) break;
        }
    }
}

extern "C" void kernel_launch(void* const* d_in, const int* in_sizes, int n_in,
                              void* d_out, int out_size, void* d_ws, size_t ws_size,
                              hipStream_t stream) {
    const float* pts = (const float*)d_in[0];   // [16, 3, 32768] fp32
    float* out = (float*)d_out;                 // [16, 3, 2048] fp32
    ull* ws = (ull*)d_ws;                       // 16 x 320 words = 40 KB used
    void* args[] = { (void*)&pts, (void*)&out, (void*)&ws };
    hipLaunchCooperativeKernel((const void*)fps_kernel,
                               dim3(FPS_B * BLK_PER_B), dim3(FPS_T),
                               args, 0, stream);
}